// Round 1
// 3763.716 us; speedup vs baseline: 1.4188x; 1.4188x over previous
//
#include <hip/hip_runtime.h>
#include <stdint.h>

#define B_   64
#define T_   512
#define NI   64
#define H_   1024
#define TH_  256   // T_HARM
#define TS_  256   // T_SPIKE
#define NB   64    // blocks in cooperative harmonic kernel
#define CPB  16    // hidden columns per block (NB*CPB == H_)
#define BH   (B_ * H_)

#define DT_      0.042f
#define THRESH_  0.008f
#define RESET_   0.001f
#define SC_      256.0f            // 2^8 scale keeps fp16 residuals normal
#define ISC2_    (1.0f / 65536.0f) // exact 2^-16 unscale

typedef _Float16 f16x8 __attribute__((ext_vector_type(8)));
typedef float    f32x4 __attribute__((ext_vector_type(4)));

union H16 { _Float16 f; unsigned short u; };

// split v*SC_ into fp16 head + fp16 residual (22+ bit combined mantissa)
__device__ __forceinline__ void split2(float s, unsigned short& uh, unsigned short& ul) {
    _Float16 h = (_Float16)s;
    float r = s - (float)h;
    _Float16 l = (_Float16)r;
    H16 a, b; a.f = h; b.f = l;
    uh = a.u; ul = b.u;
}

// ---------------------------------------------------------------------------
// Kernel 1: xw_s[t][b][n] = x[b,t,:] @ x2h[:,n] with r2-spike's EXACT
// summation order (p0..p3 strided-4 fmaf, (p0+p1)+(p2+p3)) -> bit-identical
// xwv feeding the u-chain.
// ---------------------------------------------------------------------------
__global__ __launch_bounds__(256) void xw2_kernel(
    const float* __restrict__ x, const float* __restrict__ x2h,
    float* __restrict__ xw_s)
{
    const int n  = blockIdx.x * 256 + threadIdx.x;  // 0..1023
    const int b  = blockIdx.y;                      // 0..63
    const int t0 = blockIdx.z * 64;                 // 4 t-chunks

    float w2[NI];
    #pragma unroll
    for (int k = 0; k < NI; ++k) w2[k] = x2h[(size_t)k * H_ + n];

    const float* xb = x + (size_t)b * (T_ * NI);
    #pragma unroll 2
    for (int t = t0; t < t0 + 64; ++t) {
        const float* xt = xb + (size_t)t * NI;      // wave-uniform
        float p0 = 0.f, p1 = 0.f, p2 = 0.f, p3 = 0.f;
        #pragma unroll
        for (int k = 0; k < NI; k += 4) {
            p0 = fmaf(xt[k],     w2[k],     p0);
            p1 = fmaf(xt[k + 1], w2[k + 1], p1);
            p2 = fmaf(xt[k + 2], w2[k + 2], p2);
            p3 = fmaf(xt[k + 3], w2[k + 3], p3);
        }
        xw_s[(size_t)t * BH + (size_t)b * H_ + n] = (p0 + p1) + (p2 + p3);
    }
}

// ---------------------------------------------------------------------------
// Kernel 2: harmonic recurrence — r2 arithmetic bit-for-bit (fp16x2 xin MFMA,
// XT/X2 staging, update order, publish).
//
// Barrier redesign this round (latency, not numerics):
//  * NO per-step __threadfence(). Per-step agent fences compile to
//    buffer_wbl2 (full dirty-L2 writeback: flushes the streamed hys/hzs
//    lines on the critical path) + buffer_inv (full L2 invalidate: forces
//    x/h2h refetch every step). Release ordering is already given by
//    __syncthreads()'s vmcnt(0) drain: the pub stores are agent-scope sc1
//    accesses that are COMPLETE at the coherence point (IF) when vmcnt==0,
//    so a flag store issued after that is observed-after by construction.
//    Acquire freshness holds because each step's A-loads target a pub slice
//    (time-indexed, 257 disjoint slices) this XCD has never read before:
//    no stale L1/L2 line can exist — except lines pre-dating the kernel
//    (workspace poison), killed ONCE by a single __threadfence() after the
//    t=0 barrier.
//  * hys/hzs streaming stores + XT staging moved AFTER the flag store, into
//    the poll window: the pre-flag vmcnt drain now covers only the 2 KB of
//    pub publish stores, not 8 KB of HBM streaming stores.
// ---------------------------------------------------------------------------
__global__ __launch_bounds__(256, 1) void harm_kernel(
    const float* __restrict__ x,    const float* __restrict__ x2h,
    const float* __restrict__ h2h,  const float* __restrict__ bias,
    const float* __restrict__ gam,  const float* __restrict__ eps,
    unsigned short* __restrict__ pub,   // [TH_+1][2][B][H] fp16 bits
    float* __restrict__ hys, float* __restrict__ hzs,
    float* __restrict__ hyW, float* __restrict__ hyf, float* __restrict__ hzf,
    int* __restrict__ flags)
{
    __shared__ __align__(16) unsigned short W3[2][CPB][1024]; // 64 KB h2h*SC split
    __shared__ __align__(16) unsigned short XT[2][2][4096];   // 32 KB xt*SC split (dbuf)
    __shared__ __align__(16) unsigned short X2[2][CPB][64];   //  4 KB x2h*SC split

    const int tid  = threadIdx.x;
    const int lane = tid & 63;
    const int wv   = tid >> 6;
    const int cb   = blockIdx.x * CPB;

    // ---- stage h2h[:, cb:cb+CPB] * SC, split hi/lo, XOR-swizzled (r2 verbatim) ----
    for (int idx = tid; idx < 1024 * CPB; idx += 256) {
        int c = idx & (CPB - 1);
        int k = idx >> 4;
        float w = h2h[(size_t)k * H_ + cb + c] * SC_;
        unsigned short hh, ll; split2(w, hh, ll);
        int el = c * 1024 + (((k >> 3) ^ (c & 7)) << 3) + (k & 7);
        W3[0][0][el] = hh;
        W3[1][0][el] = ll;
    }
    // ---- stage x2h[:, cb:cb+CPB] * SC (K=64) (r2 verbatim) ----
    for (int idx = tid; idx < 64 * CPB; idx += 256) {
        int c = idx & (CPB - 1);
        int k = idx >> 4;
        float w = x2h[(size_t)k * H_ + cb + c] * SC_;
        unsigned short hh, ll; split2(w, hh, ll);
        int el = c * 64 + (((k >> 3) ^ (c & 7)) << 3) + (k & 7);
        X2[0][0][el] = hh;
        X2[1][0][el] = ll;
    }

    // per-lane MFMA coordinates (validated r2)
    const int nloc = lane & 15;           // C/D col + B col
    const int ng   = cb + nloc;
    const int quad = lane >> 4;
    const int b0   = wv * 16 + quad * 4;  // C/D row = b0 + r
    const int arow = wv * 16 + nloc;      // A row (batch index)
    const int koff = quad * 8;            // A k-offset
    const float bsv = bias[ng], gmv = gam[ng], epv = eps[ng];

    float hy[4] = {0.f, 0.f, 0.f, 0.f};
    float hz[4] = {0.f, 0.f, 0.f, 0.f};

    // hy_0 = 0 publish (r2 verbatim)
    #pragma unroll
    for (int r = 0; r < 4; ++r) {
        __hip_atomic_store(&pub[(size_t)0 * BH + (size_t)(b0 + r) * H_ + ng],
                           (unsigned short)0, __ATOMIC_RELAXED, __HIP_MEMORY_SCOPE_AGENT);
        __hip_atomic_store(&pub[(size_t)1 * BH + (size_t)(b0 + r) * H_ + ng],
                           (unsigned short)0, __ATOMIC_RELAXED, __HIP_MEMORY_SCOPE_AGENT);
    }

    // stage xt for t=0 into buffer 0 (r2 verbatim)
    {
        for (int idx = tid; idx < 4096; idx += 256) {
            int b = idx >> 6, k = idx & 63;
            float v = x[(size_t)b * (T_ * NI) + 0 * NI + k] * SC_;
            unsigned short hh, ll; split2(v, hh, ll);
            int el = b * 64 + (((k >> 3) ^ (b & 7)) << 3) + (k & 7);
            XT[0][0][el] = hh;
            XT[0][1][el] = ll;
        }
    }

    // ---- initial barrier (publishes the zero state) ----
    __syncthreads();   // drains vmcnt: zero-publishes complete at coherence pt
    if (tid == 0)
        __hip_atomic_store(&flags[blockIdx.x], 1,
                           __ATOMIC_RELAXED, __HIP_MEMORY_SCOPE_AGENT);
    if (tid < NB) {
        while (__hip_atomic_load(&flags[tid], __ATOMIC_RELAXED,
                                 __HIP_MEMORY_SCOPE_AGENT) < 1)
            __builtin_amdgcn_s_sleep(1);
    }
    __syncthreads();
    __threadfence();   // ONE-TIME acquire: drop pre-kernel (poison) L2 lines

    for (int t = 0; t < TH_; ++t) {
        const int cur = t & 1;
        const unsigned short* ph = pub + ((size_t)t * 2 + 0) * BH + (size_t)arow * H_ + koff;
        const unsigned short* pl = pub + ((size_t)t * 2 + 1) * BH + (size_t)arow * H_ + koff;

        // ---- full-K prefetch of A into registers (r3-validated; same addresses) ----
        f16x8 Ah[32], Al[32];
        #pragma unroll
        for (int c = 0; c < 32; ++c) Ah[c] = *(const f16x8*)(ph + c * 32);
        #pragma unroll
        for (int c = 0; c < 32; ++c) Al[c] = *(const f16x8*)(pl + c * 32);

        // ---- xin = (xt*SC @ x2h*SC) via fp16x2 MFMA, K=64 (r2 verbatim;
        //      overlaps the A-load latency) ----
        f32x4 aX = {0.f, 0.f, 0.f, 0.f};
        #pragma unroll
        for (int kb = 0; kb < 64; kb += 32) {
            int pos = ((kb >> 3) + quad) ^ (nloc & 7);
            f16x8 ah = *(const f16x8*)&XT[cur][0][arow * 64 + pos * 8];
            f16x8 al = *(const f16x8*)&XT[cur][1][arow * 64 + pos * 8];
            f16x8 bh = *(const f16x8*)&X2[0][nloc][pos * 8];
            f16x8 bl = *(const f16x8*)&X2[1][nloc][pos * 8];
            aX = __builtin_amdgcn_mfma_f32_16x16x32_f16(ah, bh, aX, 0, 0, 0);
            aX = __builtin_amdgcn_mfma_f32_16x16x32_f16(ah, bl, aX, 0, 0, 0);
            aX = __builtin_amdgcn_mfma_f32_16x16x32_f16(al, bh, aX, 0, 0, 0);
        }

        // ---- hy @ h2h via fp16x2 MFMA, K=1024 (same accumulate order as r2) ----
        f32x4 aH = {0.f, 0.f, 0.f, 0.f};
        #pragma unroll
        for (int c = 0; c < 32; ++c) {
            int pos = (c * 4 + quad) ^ (nloc & 7);
            f16x8 bh = *(const f16x8*)&W3[0][nloc][pos * 8];
            f16x8 bl = *(const f16x8*)&W3[1][nloc][pos * 8];
            aH = __builtin_amdgcn_mfma_f32_16x16x32_f16(Ah[c], bh, aH, 0, 0, 0);
            aH = __builtin_amdgcn_mfma_f32_16x16x32_f16(Ah[c], bl, aH, 0, 0, 0);
            aH = __builtin_amdgcn_mfma_f32_16x16x32_f16(Al[c], bh, aH, 0, 0, 0);
        }

        unsigned short* pnh = pub + ((size_t)(t + 1) * 2 + 0) * BH;
        unsigned short* pnl = pub + ((size_t)(t + 1) * 2 + 1) * BH;

        // ---- state update + publish ONLY (r2 arithmetic verbatim) ----
        #pragma unroll
        for (int r = 0; r < 4; ++r) {
            int b = b0 + r;
            float hyr = hy[r], hzr = hz[r];
            float th;
            {
                #pragma clang fp contract(off)
                float xinv = aX[r] * ISC2_;        // exact unscale (r2 verbatim)
                float hywv = aH[r] * ISC2_;        // exact unscale
                float arg  = (xinv + hywv) + bsv;  // np order
                th = tanhf(arg);
                float g = gmv * hyr;
                float e = epv * hzr;
                float d = (th - g) - e;
                hzr = hzr + DT_ * d;
                hyr = hyr + DT_ * hzr;
            }
            hy[r] = hyr; hz[r] = hzr;
            unsigned short hh, ll; split2(hyr * SC_, hh, ll);
            __hip_atomic_store(&pnh[(size_t)b * H_ + ng], hh,
                               __ATOMIC_RELAXED, __HIP_MEMORY_SCOPE_AGENT);
            __hip_atomic_store(&pnl[(size_t)b * H_ + ng], ll,
                               __ATOMIC_RELAXED, __HIP_MEMORY_SCOPE_AGENT);
        }

        // ---- release: drain ONLY the publish stores, then raise the flag ----
        __syncthreads();   // vmcnt(0): pub stores complete at coherence pt
        if (tid == 0)
            __hip_atomic_store(&flags[blockIdx.x], t + 2,
                               __ATOMIC_RELAXED, __HIP_MEMORY_SCOPE_AGENT);

        // ---- off-critical-path: trajectory stores (values unchanged, only
        //      store placement moved; drained by NEXT step's __syncthreads) ----
        #pragma unroll
        for (int r = 0; r < 4; ++r) {
            int b = b0 + r;
            hys[(size_t)b * (T_ * H_) + (size_t)t * H_ + ng] = hy[r];
            hzs[(size_t)b * (T_ * H_) + (size_t)t * H_ + ng] = hz[r];
        }

        // ---- off-critical-path: stage xt for t+1 (x is L2-hot now: no inv) ----
        if (t + 1 < TH_) {
            for (int idx = tid; idx < 4096; idx += 256) {
                int b = idx >> 6, k = idx & 63;
                float v = x[(size_t)b * (T_ * NI) + (size_t)(t + 1) * NI + k] * SC_;
                unsigned short hh, ll; split2(v, hh, ll);
                int el = b * 64 + (((k >> 3) ^ (b & 7)) << 3) + (k & 7);
                XT[1 - cur][0][el] = hh;
                XT[1 - cur][1][el] = ll;
            }
        }

        // ---- wait for all publishers ----
        if (tid < NB) {
            while (__hip_atomic_load(&flags[tid], __ATOMIC_RELAXED,
                                     __HIP_MEMORY_SCOPE_AGENT) < t + 2)
                __builtin_amdgcn_s_sleep(1);
        }
        __syncthreads();   // also makes XT staging visible to all waves
    }

    // ---- hyW = hy_final @ h2h (from pub[256]); export final state (r2 verbatim) ----
    {
        const unsigned short* ph = pub + ((size_t)TH_ * 2 + 0) * BH + (size_t)arow * H_ + koff;
        const unsigned short* pl = pub + ((size_t)TH_ * 2 + 1) * BH + (size_t)arow * H_ + koff;
        f32x4 aH = {0.f, 0.f, 0.f, 0.f};
        #pragma unroll 4
        for (int c = 0; c < 32; ++c) {
            f16x8 ah = *(const f16x8*)(ph + c * 32);
            f16x8 al = *(const f16x8*)(pl + c * 32);
            int pos = (c * 4 + quad) ^ (nloc & 7);
            f16x8 bh = *(const f16x8*)&W3[0][nloc][pos * 8];
            f16x8 bl = *(const f16x8*)&W3[1][nloc][pos * 8];
            aH = __builtin_amdgcn_mfma_f32_16x16x32_f16(ah, bh, aH, 0, 0, 0);
            aH = __builtin_amdgcn_mfma_f32_16x16x32_f16(ah, bl, aH, 0, 0, 0);
            aH = __builtin_amdgcn_mfma_f32_16x16x32_f16(al, bh, aH, 0, 0, 0);
        }
        #pragma unroll
        for (int r = 0; r < 4; ++r) {
            int b = b0 + r;
            hyW[(size_t)b * H_ + ng] = aH[r] * ISC2_;
            hyf[(size_t)b * H_ + ng] = hy[r];
            hzf[(size_t)b * H_ + ng] = hz[r];
        }
    }
}

// ---------------------------------------------------------------------------
// Kernel 3: spiking (LIF) phase. u-chain r2-verbatim; xwv is bit-identical to
// r2's in-register dot (from xw2_kernel). Now writes ONLY the chain-dependent
// us/sp streams (hys/hzs tails moved to tail_kernel at full occupancy).
// ---------------------------------------------------------------------------
__global__ __launch_bounds__(256) void spike_kernel(
    const float* __restrict__ xw_s, const float* __restrict__ hyW,
    float* __restrict__ us,  float* __restrict__ sp)
{
    const int n = blockIdx.x * 256 + threadIdx.x;   // 0..1023
    const int b = blockIdx.y;                       // 0..63
    const float w = hyW[(size_t)b * H_ + n];

    float u = 0.f;
    float*       usp = us + (size_t)b * (TS_ * H_) + n;
    float*       spp = sp + (size_t)b * (TS_ * H_) + n;
    const float* xwp = xw_s + (size_t)b * H_ + n;

    #pragma unroll 4
    for (int t = 0; t < TS_; ++t) {
        float xwv = xwp[(size_t)t * BH];
        float spike, un = u;
        {
            #pragma clang fp contract(off)
            spike = (un > THRESH_) ? 1.f : 0.f;    // r2 verbatim
            un = (spike == 1.f) ? RESET_ : un;
            float s0 = (-un + w) + xwv;
            float m1 = s0 * 0.025f;
            float m2 = m1 * 0.042f;
            un = un + m2;
        }
        u = un;
        usp[(size_t)t * H_] = u;
        spp[(size_t)t * H_] = spike;
    }
}

// ---------------------------------------------------------------------------
// Kernel 4: broadcast hy/hz final state across the spiking-phase tail of the
// trajectories. Pure BW kernel (134 MB of constant writes) at full occupancy,
// float4 stores — replaces the strided scalar stores formerly inside
// spike_kernel's 3%-occupancy serial loop.
// ---------------------------------------------------------------------------
__global__ __launch_bounds__(256) void tail_kernel(
    const float* __restrict__ hyf, const float* __restrict__ hzf,
    float* __restrict__ hys, float* __restrict__ hzs)
{
    const int t  = blockIdx.x;    // 0..255
    const int b  = blockIdx.y;    // 0..63
    const int n4 = threadIdx.x;   // 0..255 (float4 index)

    const float4 hv = ((const float4*)(hyf + (size_t)b * H_))[n4];
    const float4 zv = ((const float4*)(hzf + (size_t)b * H_))[n4];
    const size_t row = (size_t)b * (T_ * H_) + (size_t)(TH_ + t) * H_;
    ((float4*)(hys + row))[n4] = hv;
    ((float4*)(hzs + row))[n4] = zv;
}

// ---------------------------------------------------------------------------
extern "C" void kernel_launch(void* const* d_in, const int* in_sizes, int n_in,
                              void* d_out, int out_size, void* d_ws, size_t ws_size,
                              hipStream_t stream)
{
    (void)in_sizes; (void)n_in; (void)out_size; (void)ws_size;

    const float* x    = (const float*)d_in[0];
    const float* x2h  = (const float*)d_in[1];
    const float* h2h  = (const float*)d_in[2];
    const float* bias = (const float*)d_in[3];
    const float* gam  = (const float*)d_in[4];
    const float* eps  = (const float*)d_in[5];

    float* out = (float*)d_out;
    float* hys = out;                                  // (64,512,1024)
    float* hzs = out + (size_t)B_ * T_ * H_;           // (64,512,1024)
    float* us  = out + 2 * (size_t)B_ * T_ * H_;       // (64,256,1024)
    float* sp  = us  + (size_t)B_ * TS_ * H_;          // (64,256,1024)

    char* ws = (char*)d_ws;
    float*          xw_s = (float*)ws;                         //  67,108,864 B
    unsigned short* pub  = (unsigned short*)(ws + 67108864);   //  67,371,008 B
    float*          hyW  = (float*)(ws + 134479872);           //     262,144 B
    float*          hyf  = (float*)(ws + 134479872 + 262144);  //     262,144 B
    float*          hzf  = (float*)(ws + 134479872 + 524288);  //     262,144 B
    int*            flg  = (int*)(ws + 134479872 + 786432);    //       4,096 B

    hipMemsetAsync(flg, 0, 4096, stream);   // flag array (ws is poisoned)

    xw2_kernel <<<dim3(4, 64, 4), 256, 0, stream>>>(x, x2h, xw_s);
    harm_kernel<<<dim3(NB), 256, 0, stream>>>(x, x2h, h2h, bias, gam, eps,
                                              pub, hys, hzs, hyW, hyf, hzf, flg);
    tail_kernel<<<dim3(256, 64), 256, 0, stream>>>(hyf, hzf, hys, hzs);
    spike_kernel<<<dim3(4, 64), 256, 0, stream>>>(xw_s, hyW, us, sp);
}